// Round 7
// baseline (265.518 us; speedup 1.0000x reference)
//
#include <hip/hip_runtime.h>
#include <hip/hip_bf16.h>
#include <cstdint>

#define B_SZ 8
#define NPTS 4096
#define KNN  20
#define NTOT (B_SZ * NPTS)   // 32768 points
#define PPB  8               // points per edge-kernel block

typedef unsigned int uint;
typedef unsigned short ushort;
using short8 = __attribute__((ext_vector_type(8))) short;
using f32x4  = __attribute__((ext_vector_type(4))) float;

__device__ __forceinline__ ushort f2bf(float f) {
  uint u = __float_as_uint(f);
  u += 0x7fff + ((u >> 16) & 1);          // RNE
  return (ushort)(u >> 16);
}
__device__ __forceinline__ float bf2f(ushort h) {
  return __uint_as_float(((uint)h) << 16);
}

// ---------- K1: prep = u_kernel + W3 bf16 cast, fused ----------
__global__ __launch_bounds__(256) void prep_kernel(const float* __restrict__ x,
                                                   const float* __restrict__ W1,
                                                   const float* __restrict__ W3,
                                                   ushort* __restrict__ u,
                                                   ushort* __restrict__ W3b) {
  int blk = blockIdx.x;
  if (blk < 8192) {
    int t = blk * 256 + threadIdx.x;
    int p = t >> 6, o = t & 63;
    int b = p >> 12, n = p & (NPTS - 1);
    const float* xb = x + (size_t)b * 3 * NPTS;
    float x0 = xb[n], x1 = xb[NPTS + n], x2 = xb[2 * NPTS + n];
    const float* w = W1 + o * 6;
    u[t] = f2bf(w[3] * x0 + w[4] * x1 + w[5] * x2);
  } else {
    int t = (blk - 8192) * 256 + threadIdx.x;   // 0..16383, 8 elems each
    const float4* src = reinterpret_cast<const float4*>(W3 + t * 8);
    float4 f0 = src[0], f1 = src[1];
    uint4 pk;
    pk.x = (uint)f2bf(f0.x) | ((uint)f2bf(f0.y) << 16);
    pk.y = (uint)f2bf(f0.z) | ((uint)f2bf(f0.w) << 16);
    pk.z = (uint)f2bf(f1.x) | ((uint)f2bf(f1.y) << 16);
    pk.w = (uint)f2bf(f1.z) | ((uint)f2bf(f1.w) << 16);
    *reinterpret_cast<uint4*>(W3b + t * 8) = pk;
  }
}

// ---------- kNN helpers ----------
__device__ __forceinline__ void sortf64(float& v, int lane) {
  #pragma unroll
  for (int k = 2; k <= 64; k <<= 1) {
    #pragma unroll
    for (int j = k >> 1; j > 0; j >>= 1) {
      float o = __shfl_xor(v, j, 64);
      bool keepmin = (((lane & k) == 0) == ((lane & j) == 0));
      bool lt = v < o;
      v = (keepmin == lt) ? v : o;
    }
  }
}

__device__ __forceinline__ void sortu64(unsigned long long& v, int lane) {
  #pragma unroll
  for (int k = 2; k <= 64; k <<= 1) {
    #pragma unroll
    for (int j = k >> 1; j > 0; j >>= 1) {
      unsigned long long o = __shfl_xor(v, j, 64);
      bool keepmin = (((lane & k) == 0) == ((lane & j) == 0));
      bool lt = v < o;
      v = (keepmin == lt) ? v : o;
    }
  }
}

// ---------- K2: kNN — single distance pass + u16 LDS keys, one wave/row ----------
// Pass A computes each distance ONCE, stores key16 = float_bits(d)>>16 in LDS
// (monotone for d>=0), tracks per-lane float min. T = 20th-smallest lane-min;
// filter key16 <= T16. Survivors atomic-appended (order nondeterministic, but
// the final bitonic ranks full (dist,idx) keys, so the output top-20 is exact
// and deterministic for any append order). >=20 survivors structurally
// guaranteed (integer-domain, same stored keys both passes).
__global__ __launch_bounds__(64, 4) void knn_kernel(const float* __restrict__ x,
                                                    int* __restrict__ idx_out) {
  __shared__ ushort keys[NPTS];     // 8 KB
  __shared__ int    surv[256];      // 1 KB
  __shared__ int    cnt;
  const unsigned long long INFK = ~0ull;
  int row = blockIdx.x;
  int b = row >> 12, n = row & (NPTS - 1);
  int lane = threadIdx.x;
  const float* xb = x + (size_t)b * 3 * NPTS;
  float qx = xb[n], qy = xb[NPTS + n], qz = xb[2 * NPTS + n];
  if (lane == 0) cnt = 0;

  const float4* X0 = reinterpret_cast<const float4*>(xb);
  const float4* X1 = reinterpret_cast<const float4*>(xb + NPTS);
  const float4* X2 = reinterpret_cast<const float4*>(xb + 2 * NPTS);

  // pass A: distances -> u16 keys in LDS, per-lane float min in regs
  float bm = 3.0e38f;
  #pragma unroll 4
  for (int i = 0; i < 16; ++i) {
    int v4 = i * 64 + lane;
    float4 a0 = X0[v4], a1 = X1[v4], a2 = X2[v4];
    float dx, dy, dz, d0, d1, d2, d3;
    dx = a0.x - qx; dy = a1.x - qy; dz = a2.x - qz; d0 = dx*dx + dy*dy + dz*dz;
    dx = a0.y - qx; dy = a1.y - qy; dz = a2.y - qz; d1 = dx*dx + dy*dy + dz*dz;
    dx = a0.z - qx; dy = a1.z - qy; dz = a2.z - qz; d2 = dx*dx + dy*dy + dz*dz;
    dx = a0.w - qx; dy = a1.w - qy; dz = a2.w - qz; d3 = dx*dx + dy*dy + dz*dz;
    bm = fminf(bm, fminf(fminf(d0, d1), fminf(d2, d3)));
    uint2 kk;
    kk.x = (__float_as_uint(d0) >> 16) | (__float_as_uint(d1) & 0xFFFF0000u);
    kk.y = (__float_as_uint(d2) >> 16) | (__float_as_uint(d3) & 0xFFFF0000u);
    *reinterpret_cast<uint2*>(&keys[v4 * 4]) = kk;   // ds_write_b64
  }

  // threshold
  sortf64(bm, lane);
  float T = __shfl(bm, 19, 64);
  uint T16 = __float_as_uint(T) >> 16;
  __syncthreads();

  // pass B: integer filter on stored keys, atomic-append survivor indices
  #pragma unroll 4
  for (int i = 0; i < 16; ++i) {
    int v4 = i * 64 + lane;
    uint2 kk = *reinterpret_cast<const uint2*>(&keys[v4 * 4]);
    uint k0 = kk.x & 0xffffu, k1 = kk.x >> 16, k2 = kk.y & 0xffffu, k3 = kk.y >> 16;
    int m0 = v4 * 4;
    if (k0 <= T16) { int s = atomicAdd(&cnt, 1); if (s < 256) surv[s] = m0; }
    if (k1 <= T16) { int s = atomicAdd(&cnt, 1); if (s < 256) surv[s] = m0 + 1; }
    if (k2 <= T16) { int s = atomicAdd(&cnt, 1); if (s < 256) surv[s] = m0 + 2; }
    if (k3 <= T16) { int s = atomicAdd(&cnt, 1); if (s < 256) surv[s] = m0 + 3; }
  }
  __syncthreads();
  int M = cnt;

  if (M <= 256) {   // M >= 20 guaranteed structurally
    // exact d for survivors only, chunked bitonic top-20
    unsigned long long run = INFK;
    int nch = (M + 63) >> 6;
    for (int c = 0; c < nch; ++c) {
      int s = c * 64 + lane;
      unsigned long long v = INFK;
      if (s < M) {
        int m = surv[s];
        float dx = xb[m] - qx, dy = xb[NPTS + m] - qy, dz = xb[2 * NPTS + m] - qz;
        float d = dx * dx + dy * dy + dz * dz;
        v = ((unsigned long long)__float_as_uint(d) << 32) | (unsigned)m;
      }
      sortu64(v, lane);
      if (c == 0) {
        run = v;
      } else {
        unsigned long long b19 = __shfl(v, (19 - lane) & 63, 64);
        unsigned long long cand = run < b19 ? run : b19;
        run = (lane < KNN) ? cand : INFK;
        sortu64(run, lane);
      }
    }
    if (lane < KNN) idx_out[(size_t)row * KNN + lane] = (int)(run & 0xFFFFFFFFull);
  } else {
    // pathological fallback (tie storms): exact threshold-free 20-round extraction
    unsigned long long prev = 0ull;
    for (int r = 0; r < KNN; ++r) {
      unsigned long long best = INFK;
      for (int i = 0; i < 16; ++i) {
        int v4 = i * 64 + lane;
        float4 a0 = X0[v4], a1 = X1[v4], a2 = X2[v4];
        float dx, dy, dz, d[4];
        dx = a0.x - qx; dy = a1.x - qy; dz = a2.x - qz; d[0] = dx*dx + dy*dy + dz*dz;
        dx = a0.y - qx; dy = a1.y - qy; dz = a2.y - qz; d[1] = dx*dx + dy*dy + dz*dz;
        dx = a0.z - qx; dy = a1.z - qy; dz = a2.z - qz; d[2] = dx*dx + dy*dy + dz*dz;
        dx = a0.w - qx; dy = a1.w - qy; dz = a2.w - qz; d[3] = dx*dx + dy*dy + dz*dz;
        #pragma unroll
        for (int j = 0; j < 4; ++j) {
          int m = i * 256 + lane * 4 + j;
          unsigned long long key =
              ((unsigned long long)__float_as_uint(d[j]) << 32) | (unsigned)m;
          if ((r == 0 || key > prev) && key < best) best = key;
        }
      }
      #pragma unroll
      for (int off = 32; off; off >>= 1) {
        unsigned long long o = __shfl_xor(best, off, 64);
        best = o < best ? o : best;
      }
      if (lane == 0) idx_out[(size_t)row * KNN + r] = (int)(best & 0xFFFFFFFFull);
      prev = best;
    }
  }
}

// ---------- K3: edge conv via MFMA (unchanged) ----------
__global__ __launch_bounds__(256, 2) void edge_kernel(
    const float* __restrict__ x,  const float* __restrict__ W1, const float* __restrict__ b1,
    const float* __restrict__ W2, const float* __restrict__ b2,
    const ushort* __restrict__ u, const int* __restrict__ idx,
    float* __restrict__ h128) {
  __shared__ __align__(16) char w2s[128 * 128];          // 16 KB
  __shared__ __align__(16) char h1s[PPB * 32 * 128];     // 32 KB
  __shared__ float vs[PPB * 64];                         // 2 KB
  __shared__ int   nbs[PPB * KNN];

  int tid = threadIdx.x, w = tid >> 6, l = tid & 63;
  int p0 = blockIdx.x * PPB;
  int b = p0 >> 12;
  const float* xb = x + (size_t)b * 3 * NPTS;

  for (int e = tid; e < 1024; e += 256) {
    int row = e >> 3, c0 = (e & 7) * 8;
    const float* wp = W2 + row * 64 + c0;
    float4 f0 = *(const float4*)wp, f1 = *(const float4*)(wp + 4);
    uint4 pk;
    pk.x = (uint)f2bf(f0.x) | ((uint)f2bf(f0.y) << 16);
    pk.y = (uint)f2bf(f0.z) | ((uint)f2bf(f0.w) << 16);
    pk.z = (uint)f2bf(f1.x) | ((uint)f2bf(f1.y) << 16);
    pk.w = (uint)f2bf(f1.z) | ((uint)f2bf(f1.w) << 16);
    int byte = (row * 128 + c0 * 2) ^ ((row & 7) << 4);
    *(uint4*)(w2s + byte) = pk;
  }
  for (int t = tid; t < PPB * 64; t += 256) {
    int p = t >> 6, c = t & 63;
    int n = (p0 + p) & (NPTS - 1);
    float x0 = xb[n], x1 = xb[NPTS + n], x2 = xb[2 * NPTS + n];
    const float* wr = W1 + c * 6;
    vs[t] = (wr[0] - wr[3]) * x0 + (wr[1] - wr[4]) * x1 + (wr[2] - wr[5]) * x2 + b1[c];
  }
  if (tid < PPB * KNN) nbs[tid] = idx[(size_t)p0 * KNN + tid];
  __syncthreads();

  const ushort* ub = u + (((size_t)b) << 12) * 64;
  #pragma unroll
  for (int j = 0; j < 8; ++j) {
    int e_loc = j * 8 + (l >> 3);
    int p_loc = (w << 1) + (e_loc >> 5);
    int e_in = e_loc & 31;
    int e_src = (e_in < KNN) ? e_in : e_in - KNN;
    int nb = nbs[p_loc * KNN + e_src];
    int c0 = (l & 7) * 8;
    uint4 uv = *(const uint4*)(ub + (((size_t)nb) << 6) + c0);
    const float* vp = vs + p_loc * 64 + c0;
    float4 v0 = *(const float4*)vp, v1 = *(const float4*)(vp + 4);
    float h0 = fmaxf(bf2f((ushort)(uv.x & 0xffff)) + v0.x, 0.f);
    float h1 = fmaxf(bf2f((ushort)(uv.x >> 16))    + v0.y, 0.f);
    float h2 = fmaxf(bf2f((ushort)(uv.y & 0xffff)) + v0.z, 0.f);
    float h3 = fmaxf(bf2f((ushort)(uv.y >> 16))    + v0.w, 0.f);
    float h4 = fmaxf(bf2f((ushort)(uv.z & 0xffff)) + v1.x, 0.f);
    float h5 = fmaxf(bf2f((ushort)(uv.z >> 16))    + v1.y, 0.f);
    float h6 = fmaxf(bf2f((ushort)(uv.w & 0xffff)) + v1.z, 0.f);
    float h7 = fmaxf(bf2f((ushort)(uv.w >> 16))    + v1.w, 0.f);
    uint4 pk;
    pk.x = (uint)f2bf(h0) | ((uint)f2bf(h1) << 16);
    pk.y = (uint)f2bf(h2) | ((uint)f2bf(h3) << 16);
    pk.z = (uint)f2bf(h4) | ((uint)f2bf(h5) << 16);
    pk.w = (uint)f2bf(h6) | ((uint)f2bf(h7) << 16);
    int row = (w << 6) + e_loc;
    int byte = (row * 128 + c0 * 2) ^ ((row & 7) << 4);
    *(uint4*)(h1s + byte) = pk;
  }
  __syncthreads();

  short8 bfr[8][2];
  #pragma unroll
  for (int nt = 0; nt < 8; ++nt) {
    #pragma unroll
    for (int ks = 0; ks < 2; ++ks) {
      int row = nt * 16 + (l & 15);
      int byte = (row * 128 + ks * 64 + (l >> 4) * 16) ^ ((row & 7) << 4);
      bfr[nt][ks] = *(const short8*)(w2s + byte);
    }
  }
  float bias0 = b2[l], bias1 = b2[64 + l];

  #pragma unroll
  for (int pt = 0; pt < 2; ++pt) {
    int rbase = (w << 6) + (pt << 5);
    short8 a[2][2];
    #pragma unroll
    for (int m = 0; m < 2; ++m) {
      #pragma unroll
      for (int ks = 0; ks < 2; ++ks) {
        int row = rbase + m * 16 + (l & 15);
        int byte = (row * 128 + ks * 64 + (l >> 4) * 16) ^ ((row & 7) << 4);
        a[m][ks] = *(const short8*)(h1s + byte);
      }
    }
    float r03 = 0.f, r47 = 0.f;
    #pragma unroll
    for (int nt = 0; nt < 8; ++nt) {
      f32x4 acc0 = {0.f, 0.f, 0.f, 0.f}, acc1 = {0.f, 0.f, 0.f, 0.f};
      acc0 = __builtin_amdgcn_mfma_f32_16x16x32_bf16(a[0][0], bfr[nt][0], acc0, 0, 0, 0);
      acc0 = __builtin_amdgcn_mfma_f32_16x16x32_bf16(a[0][1], bfr[nt][1], acc0, 0, 0, 0);
      acc1 = __builtin_amdgcn_mfma_f32_16x16x32_bf16(a[1][0], bfr[nt][0], acc1, 0, 0, 0);
      acc1 = __builtin_amdgcn_mfma_f32_16x16x32_bf16(a[1][1], bfr[nt][1], acc1, 0, 0, 0);
      float m0 = fmaxf(fmaxf(fmaxf(acc0[0], acc1[0]), fmaxf(acc0[1], acc1[1])),
                       fmaxf(fmaxf(acc0[2], acc1[2]), fmaxf(acc0[3], acc1[3])));
      m0 = fmaxf(m0, __shfl_xor(m0, 16, 64));
      m0 = fmaxf(m0, __shfl_xor(m0, 32, 64));
      if ((l >> 4) == (nt & 3)) { if (nt < 4) r03 = m0; else r47 = m0; }
    }
    int pg = p0 + (w << 1) + pt;
    h128[(size_t)pg * 128 + l]      = fmaxf(r03 + bias0, 0.f);
    h128[(size_t)pg * 128 + 64 + l] = fmaxf(r47 + bias1, 0.f);
  }
}

// ---------- K4: inter via MFMA (unchanged) ----------
__global__ __launch_bounds__(256, 2) void inter_kernel(
    const float* __restrict__ h128, const ushort* __restrict__ W3b,
    float* __restrict__ partial) {
  __shared__ __align__(16) char as_[32 * 256];   // 8 KB
  int tid = threadIdx.x, w = tid >> 6, l = tid & 63;
  int chunk = blockIdx.x;
  const float* hp = h128 + (size_t)chunk * 32 * 128;

  {
    int row = tid >> 3, c0 = (tid & 7) * 16;
    const float4* src = reinterpret_cast<const float4*>(hp + row * 128 + c0);
    float4 f0 = src[0], f1 = src[1], f2 = src[2], f3 = src[3];
    uint4 p0, p1;
    p0.x = (uint)f2bf(f0.x) | ((uint)f2bf(f0.y) << 16);
    p0.y = (uint)f2bf(f0.z) | ((uint)f2bf(f0.w) << 16);
    p0.z = (uint)f2bf(f1.x) | ((uint)f2bf(f1.y) << 16);
    p0.w = (uint)f2bf(f1.z) | ((uint)f2bf(f1.w) << 16);
    p1.x = (uint)f2bf(f2.x) | ((uint)f2bf(f2.y) << 16);
    p1.y = (uint)f2bf(f2.z) | ((uint)f2bf(f2.w) << 16);
    p1.z = (uint)f2bf(f3.x) | ((uint)f2bf(f3.y) << 16);
    p1.w = (uint)f2bf(f3.z) | ((uint)f2bf(f3.w) << 16);
    int sw = (row & 7) << 4;
    *(uint4*)(as_ + ((row * 256 + c0 * 2) ^ sw))      = p0;
    *(uint4*)(as_ + ((row * 256 + c0 * 2 + 16) ^ sw)) = p1;
  }
  __syncthreads();

  short8 a[2][4];
  #pragma unroll
  for (int m = 0; m < 2; ++m) {
    #pragma unroll
    for (int ks = 0; ks < 4; ++ks) {
      int row = m * 16 + (l & 15);
      int byte = (row * 256 + ks * 64 + (l >> 4) * 16) ^ ((row & 7) << 4);
      a[m][ks] = *(const short8*)(as_ + byte);
    }
  }

  const ushort* wb = W3b + (size_t)(w * 256) * 128;
  float res[4];
  #pragma unroll
  for (int nt = 0; nt < 16; ++nt) {
    f32x4 acc0 = {0.f, 0.f, 0.f, 0.f}, acc1 = {0.f, 0.f, 0.f, 0.f};
    #pragma unroll
    for (int ks = 0; ks < 4; ++ks) {
      short8 bf = *(const short8*)(wb + (size_t)(nt * 16 + (l & 15)) * 128
                                      + ks * 32 + (l >> 4) * 8);
      acc0 = __builtin_amdgcn_mfma_f32_16x16x32_bf16(a[0][ks], bf, acc0, 0, 0, 0);
      acc1 = __builtin_amdgcn_mfma_f32_16x16x32_bf16(a[1][ks], bf, acc1, 0, 0, 0);
    }
    float m0 = fmaxf(fmaxf(fmaxf(acc0[0], acc1[0]), fmaxf(acc0[1], acc1[1])),
                     fmaxf(fmaxf(acc0[2], acc1[2]), fmaxf(acc0[3], acc1[3])));
    m0 = fmaxf(m0, __shfl_xor(m0, 16, 64));
    m0 = fmaxf(m0, __shfl_xor(m0, 32, 64));
    if ((l >> 4) == (nt & 3)) res[nt >> 2] = m0;
  }
  float* pp = partial + (size_t)chunk * 1024 + w * 256;
  #pragma unroll
  for (int g = 0; g < 4; ++g) pp[g * 64 + l] = res[g];
}

// ---------- K5: global max over chunks + bias + relu (32 blocks) ----------
__global__ __launch_bounds__(256) void gmax_kernel(const float* __restrict__ partial,
                                                   const float* __restrict__ b3,
                                                   float* __restrict__ g) {
  int t = blockIdx.x * 256 + threadIdx.x;
  if (t >= B_SZ * 1024) return;
  int b = t >> 10, ch = t & 1023;
  const float* p = partial + (size_t)b * 128 * 1024 + ch;
  float m = -3.0e38f;
  for (int i = 0; i < 128; ++i) m = fmaxf(m, p[(size_t)i * 1024]);
  g[t] = fmaxf(m + b3[ch], 0.0f);
}

// ---------- K6: fc4+fc5+fc6 fused, one block per batch (small, matched parallelism) ----------
__global__ __launch_bounds__(256) void fc_fused_kernel(
    const float* __restrict__ g,
    const float* __restrict__ W4, const float* __restrict__ b4,
    const float* __restrict__ W5, const float* __restrict__ b5,
    const float* __restrict__ W6, const float* __restrict__ b6,
    float* __restrict__ out) {
  __shared__ float gs[1024];
  __shared__ float g4s[512];
  __shared__ float g5s[256];
  int b = blockIdx.x, t = threadIdx.x;

  *(float4*)(gs + t * 4) = *(const float4*)(g + b * 1024 + t * 4);
  __syncthreads();

  { // fc4 1024->512: thread t -> outputs t, t+256
    float s0 = 0.f, s1 = 0.f;
    const float* w0 = W4 + (size_t)t * 1024;
    const float* w1 = W4 + (size_t)(t + 256) * 1024;
    for (int c = 0; c < 1024; c += 4) {
      float4 gv = *(const float4*)(gs + c);
      float4 a0 = *(const float4*)(w0 + c);
      float4 a1 = *(const float4*)(w1 + c);
      s0 += gv.x*a0.x + gv.y*a0.y + gv.z*a0.z + gv.w*a0.w;
      s1 += gv.x*a1.x + gv.y*a1.y + gv.z*a1.z + gv.w*a1.w;
    }
    g4s[t]       = fmaxf(s0 + b4[t], 0.f);
    g4s[t + 256] = fmaxf(s1 + b4[t + 256], 0.f);
  }
  __syncthreads();

  { // fc5 512->256
    if (t < 256) {
      float s = 0.f;
      const float* w = W5 + (size_t)t * 512;
      for (int c = 0; c < 512; c += 4) {
        float4 gv = *(const float4*)(g4s + c);
        float4 a  = *(const float4*)(w + c);
        s += gv.x*a.x + gv.y*a.y + gv.z*a.z + gv.w*a.w;
      }
      g5s[t] = fmaxf(s + b5[t], 0.f);
    }
  }
  __syncthreads();

  if (t < 9) { // fc6 256->9 + eye(3)
    float s = 0.f;
    const float* w = W6 + t * 256;
    for (int c = 0; c < 256; ++c) s += g5s[c] * w[c];
    s += b6[t];
    if (t == 0 || t == 4 || t == 8) s += 1.0f;
    out[b * 9 + t] = s;
  }
}

extern "C" void kernel_launch(void* const* d_in, const int* in_sizes, int n_in,
                              void* d_out, int out_size, void* d_ws, size_t ws_size,
                              hipStream_t stream) {
  const float* x  = (const float*)d_in[0];
  const float* W1 = (const float*)d_in[1];
  const float* b1 = (const float*)d_in[2];
  const float* W2 = (const float*)d_in[3];
  const float* b2 = (const float*)d_in[4];
  const float* W3 = (const float*)d_in[5];
  const float* b3 = (const float*)d_in[6];
  const float* W4 = (const float*)d_in[7];
  const float* b4 = (const float*)d_in[8];
  const float* W5 = (const float*)d_in[9];
  const float* b5 = (const float*)d_in[10];
  const float* W6 = (const float*)d_in[11];
  const float* b6 = (const float*)d_in[12];
  float* out = (float*)d_out;

  char* ws = (char*)d_ws;
  ushort* u_bf = (ushort*)(ws);                  // [0,4M)   dead after edge_kernel
  int*   idxb  = (int*)  (ws + (8u  << 20));     // [8,10.5M) dead after edge_kernel
  float* h128  = (float*)(ws + (11u << 20));     // [11,27M)
  ushort* W3b  = (ushort*)(ws + (27u << 20));    // [27,27.25M)
  float* part  = (float*)(ws);                   // [0,4M)  over dead u
  float* g     = (float*)(ws + (5u  << 20));     // [5,5.03M)

  hipLaunchKernelGGL(prep_kernel, dim3(8256), dim3(256), 0, stream, x, W1, W3, u_bf, W3b);
  hipLaunchKernelGGL(knn_kernel,  dim3(32768), dim3(64), 0, stream, x, idxb);
  hipLaunchKernelGGL(edge_kernel, dim3(NTOT / PPB), dim3(256), 0, stream,
                     x, W1, b1, W2, b2, u_bf, idxb, h128);
  hipLaunchKernelGGL(inter_kernel, dim3(1024), dim3(256), 0, stream, h128, W3b, part);
  hipLaunchKernelGGL(gmax_kernel, dim3(32), dim3(256), 0, stream, part, b3, g);
  hipLaunchKernelGGL(fc_fused_kernel, dim3(B_SZ), dim3(256), 0, stream,
                     g, W4, b4, W5, b5, W6, b6, out);
}

// Round 8
// 179.951 us; speedup vs baseline: 1.4755x; 1.4755x over previous
//
#include <hip/hip_runtime.h>
#include <hip/hip_bf16.h>
#include <cstdint>

#define B_SZ 8
#define NPTS 4096
#define KNN  20
#define NTOT (B_SZ * NPTS)   // 32768 points
#define PPB  8               // points per edge-kernel block

typedef unsigned int uint;
typedef unsigned short ushort;
using short8 = __attribute__((ext_vector_type(8))) short;
using f32x4  = __attribute__((ext_vector_type(4))) float;

__device__ __forceinline__ ushort f2bf(float f) {
  uint u = __float_as_uint(f);
  u += 0x7fff + ((u >> 16) & 1);          // RNE
  return (ushort)(u >> 16);
}
__device__ __forceinline__ float bf2f(ushort h) {
  return __uint_as_float(((uint)h) << 16);
}

// ---------- K1: prep = u_kernel + W3 bf16 cast, fused ----------
__global__ __launch_bounds__(256) void prep_kernel(const float* __restrict__ x,
                                                   const float* __restrict__ W1,
                                                   const float* __restrict__ W3,
                                                   ushort* __restrict__ u,
                                                   ushort* __restrict__ W3b) {
  int blk = blockIdx.x;
  if (blk < 8192) {
    int t = blk * 256 + threadIdx.x;
    int p = t >> 6, o = t & 63;
    int b = p >> 12, n = p & (NPTS - 1);
    const float* xb = x + (size_t)b * 3 * NPTS;
    float x0 = xb[n], x1 = xb[NPTS + n], x2 = xb[2 * NPTS + n];
    const float* w = W1 + o * 6;
    u[t] = f2bf(w[3] * x0 + w[4] * x1 + w[5] * x2);
  } else {
    int t = (blk - 8192) * 256 + threadIdx.x;   // 0..16383, 8 elems each
    const float4* src = reinterpret_cast<const float4*>(W3 + t * 8);
    float4 f0 = src[0], f1 = src[1];
    uint4 pk;
    pk.x = (uint)f2bf(f0.x) | ((uint)f2bf(f0.y) << 16);
    pk.y = (uint)f2bf(f0.z) | ((uint)f2bf(f0.w) << 16);
    pk.z = (uint)f2bf(f1.x) | ((uint)f2bf(f1.y) << 16);
    pk.w = (uint)f2bf(f1.z) | ((uint)f2bf(f1.w) << 16);
    *reinterpret_cast<uint4*>(W3b + t * 8) = pk;
  }
}

// ---------- kNN helpers ----------
__device__ __forceinline__ void sortf64(float& v, int lane) {
  #pragma unroll
  for (int k = 2; k <= 64; k <<= 1) {
    #pragma unroll
    for (int j = k >> 1; j > 0; j >>= 1) {
      float o = __shfl_xor(v, j, 64);
      bool keepmin = (((lane & k) == 0) == ((lane & j) == 0));
      bool lt = v < o;
      v = (keepmin == lt) ? v : o;
    }
  }
}

__device__ __forceinline__ void sortu64(unsigned long long& v, int lane) {
  #pragma unroll
  for (int k = 2; k <= 64; k <<= 1) {
    #pragma unroll
    for (int j = k >> 1; j > 0; j >>= 1) {
      unsigned long long o = __shfl_xor(v, j, 64);
      bool keepmin = (((lane & k) == 0) == ((lane & j) == 0));
      bool lt = v < o;
      v = (keepmin == lt) ? v : o;
    }
  }
}

// ---------- K2: kNN v3 — keys in registers, 4 independent waves/block ----------
// Wave w handles row blk*4+w. Pass A: distances once, u16 keys packed into 32
// uint REGISTERS (static unrolled indexing), per-lane float min. T = 20th-
// smallest lane-min; pass B: register compare, LDS atomic-append survivors
// (order-free: final bitonic ranks full (dist,idx) keys -> exact determinate
// top-20). >=20 survivors structurally guaranteed (same register keys both
// passes, integer compare). Waves never sync with each other: per-wave
// cnt/surv segments + own-wave s_waitcnt lgkmcnt(0).
__global__ __launch_bounds__(256, 4) void knn_kernel(const float* __restrict__ x,
                                                     int* __restrict__ idx_out) {
  __shared__ int surv[4][256];      // 4 KB
  __shared__ int cnt[4];
  const unsigned long long INFK = ~0ull;
  int w = threadIdx.x >> 6, lane = threadIdx.x & 63;
  int row = blockIdx.x * 4 + w;
  int b = row >> 12, n = row & (NPTS - 1);
  const float* xb = x + (size_t)b * 3 * NPTS;
  float qx = xb[n], qy = xb[NPTS + n], qz = xb[2 * NPTS + n];
  if (lane == 0) cnt[w] = 0;

  const float4* X0 = reinterpret_cast<const float4*>(xb);
  const float4* X1 = reinterpret_cast<const float4*>(xb + NPTS);
  const float4* X2 = reinterpret_cast<const float4*>(xb + 2 * NPTS);

  // pass A: distances -> packed u16 keys in registers, per-lane min
  uint kreg[32];
  float bm = 3.0e38f;
  #pragma unroll
  for (int i = 0; i < 16; ++i) {
    int v4 = i * 64 + lane;
    float4 a0 = X0[v4], a1 = X1[v4], a2 = X2[v4];
    float dx, dy, dz, d0, d1, d2, d3;
    dx = a0.x - qx; dy = a1.x - qy; dz = a2.x - qz; d0 = dx*dx + dy*dy + dz*dz;
    dx = a0.y - qx; dy = a1.y - qy; dz = a2.y - qz; d1 = dx*dx + dy*dy + dz*dz;
    dx = a0.z - qx; dy = a1.z - qy; dz = a2.z - qz; d2 = dx*dx + dy*dy + dz*dz;
    dx = a0.w - qx; dy = a1.w - qy; dz = a2.w - qz; d3 = dx*dx + dy*dy + dz*dz;
    bm = fminf(bm, fminf(fminf(d0, d1), fminf(d2, d3)));
    kreg[2*i]   = (__float_as_uint(d0) >> 16) | (__float_as_uint(d1) & 0xFFFF0000u);
    kreg[2*i+1] = (__float_as_uint(d2) >> 16) | (__float_as_uint(d3) & 0xFFFF0000u);
  }

  // threshold = 20th-smallest lane-min
  sortf64(bm, lane);
  float T = __shfl(bm, 19, 64);
  uint T16 = __float_as_uint(T) >> 16;

  // pass B: register filter, atomic-append (own-wave segment only)
  asm volatile("s_waitcnt lgkmcnt(0)" ::: "memory");   // cnt[w] init visible
  #pragma unroll
  for (int i = 0; i < 16; ++i) {
    uint ka = kreg[2*i], kb = kreg[2*i+1];
    int m0 = (i * 64 + lane) * 4;
    if ((ka & 0xffffu) <= T16) { int s = atomicAdd(&cnt[w], 1); if (s < 256) surv[w][s] = m0; }
    if ((ka >> 16)     <= T16) { int s = atomicAdd(&cnt[w], 1); if (s < 256) surv[w][s] = m0 + 1; }
    if ((kb & 0xffffu) <= T16) { int s = atomicAdd(&cnt[w], 1); if (s < 256) surv[w][s] = m0 + 2; }
    if ((kb >> 16)     <= T16) { int s = atomicAdd(&cnt[w], 1); if (s < 256) surv[w][s] = m0 + 3; }
  }
  asm volatile("s_waitcnt lgkmcnt(0)" ::: "memory");   // own appends complete
  int M = cnt[w];

  if (M <= 256) {   // M >= 20 guaranteed structurally
    // exact d for survivors only, chunked bitonic top-20
    unsigned long long run = INFK;
    int nch = (M + 63) >> 6;
    for (int c = 0; c < nch; ++c) {
      int s = c * 64 + lane;
      unsigned long long v = INFK;
      if (s < M) {
        int m = surv[w][s];
        float dx = xb[m] - qx, dy = xb[NPTS + m] - qy, dz = xb[2 * NPTS + m] - qz;
        float d = dx * dx + dy * dy + dz * dz;
        v = ((unsigned long long)__float_as_uint(d) << 32) | (unsigned)m;
      }
      sortu64(v, lane);
      if (c == 0) {
        run = v;
      } else {
        unsigned long long b19 = __shfl(v, (19 - lane) & 63, 64);
        unsigned long long cand = run < b19 ? run : b19;
        run = (lane < KNN) ? cand : INFK;
        sortu64(run, lane);
      }
    }
    if (lane < KNN) idx_out[(size_t)row * KNN + lane] = (int)(run & 0xFFFFFFFFull);
  } else {
    // pathological fallback (tie storms): exact threshold-free 20-round extraction
    unsigned long long prev = 0ull;
    for (int r = 0; r < KNN; ++r) {
      unsigned long long best = INFK;
      for (int i = 0; i < 16; ++i) {
        int v4 = i * 64 + lane;
        float4 a0 = X0[v4], a1 = X1[v4], a2 = X2[v4];
        float dx, dy, dz, d[4];
        dx = a0.x - qx; dy = a1.x - qy; dz = a2.x - qz; d[0] = dx*dx + dy*dy + dz*dz;
        dx = a0.y - qx; dy = a1.y - qy; dz = a2.y - qz; d[1] = dx*dx + dy*dy + dz*dz;
        dx = a0.z - qx; dy = a1.z - qy; dz = a2.z - qz; d[2] = dx*dx + dy*dy + dz*dz;
        dx = a0.w - qx; dy = a1.w - qy; dz = a2.w - qz; d[3] = dx*dx + dy*dy + dz*dz;
        #pragma unroll
        for (int j = 0; j < 4; ++j) {
          int m = i * 256 + lane * 4 + j;
          unsigned long long key =
              ((unsigned long long)__float_as_uint(d[j]) << 32) | (unsigned)m;
          if ((r == 0 || key > prev) && key < best) best = key;
        }
      }
      #pragma unroll
      for (int off = 32; off; off >>= 1) {
        unsigned long long o = __shfl_xor(best, off, 64);
        best = o < best ? o : best;
      }
      if (lane == 0) idx_out[(size_t)row * KNN + r] = (int)(best & 0xFFFFFFFFull);
      prev = best;
    }
  }
}

// ---------- K3: edge conv via MFMA (unchanged) ----------
__global__ __launch_bounds__(256, 2) void edge_kernel(
    const float* __restrict__ x,  const float* __restrict__ W1, const float* __restrict__ b1,
    const float* __restrict__ W2, const float* __restrict__ b2,
    const ushort* __restrict__ u, const int* __restrict__ idx,
    float* __restrict__ h128) {
  __shared__ __align__(16) char w2s[128 * 128];          // 16 KB
  __shared__ __align__(16) char h1s[PPB * 32 * 128];     // 32 KB
  __shared__ float vs[PPB * 64];                         // 2 KB
  __shared__ int   nbs[PPB * KNN];

  int tid = threadIdx.x, w = tid >> 6, l = tid & 63;
  int p0 = blockIdx.x * PPB;
  int b = p0 >> 12;
  const float* xb = x + (size_t)b * 3 * NPTS;

  for (int e = tid; e < 1024; e += 256) {
    int row = e >> 3, c0 = (e & 7) * 8;
    const float* wp = W2 + row * 64 + c0;
    float4 f0 = *(const float4*)wp, f1 = *(const float4*)(wp + 4);
    uint4 pk;
    pk.x = (uint)f2bf(f0.x) | ((uint)f2bf(f0.y) << 16);
    pk.y = (uint)f2bf(f0.z) | ((uint)f2bf(f0.w) << 16);
    pk.z = (uint)f2bf(f1.x) | ((uint)f2bf(f1.y) << 16);
    pk.w = (uint)f2bf(f1.z) | ((uint)f2bf(f1.w) << 16);
    int byte = (row * 128 + c0 * 2) ^ ((row & 7) << 4);
    *(uint4*)(w2s + byte) = pk;
  }
  for (int t = tid; t < PPB * 64; t += 256) {
    int p = t >> 6, c = t & 63;
    int n = (p0 + p) & (NPTS - 1);
    float x0 = xb[n], x1 = xb[NPTS + n], x2 = xb[2 * NPTS + n];
    const float* wr = W1 + c * 6;
    vs[t] = (wr[0] - wr[3]) * x0 + (wr[1] - wr[4]) * x1 + (wr[2] - wr[5]) * x2 + b1[c];
  }
  if (tid < PPB * KNN) nbs[tid] = idx[(size_t)p0 * KNN + tid];
  __syncthreads();

  const ushort* ub = u + (((size_t)b) << 12) * 64;
  #pragma unroll
  for (int j = 0; j < 8; ++j) {
    int e_loc = j * 8 + (l >> 3);
    int p_loc = (w << 1) + (e_loc >> 5);
    int e_in = e_loc & 31;
    int e_src = (e_in < KNN) ? e_in : e_in - KNN;
    int nb = nbs[p_loc * KNN + e_src];
    int c0 = (l & 7) * 8;
    uint4 uv = *(const uint4*)(ub + (((size_t)nb) << 6) + c0);
    const float* vp = vs + p_loc * 64 + c0;
    float4 v0 = *(const float4*)vp, v1 = *(const float4*)(vp + 4);
    float h0 = fmaxf(bf2f((ushort)(uv.x & 0xffff)) + v0.x, 0.f);
    float h1 = fmaxf(bf2f((ushort)(uv.x >> 16))    + v0.y, 0.f);
    float h2 = fmaxf(bf2f((ushort)(uv.y & 0xffff)) + v0.z, 0.f);
    float h3 = fmaxf(bf2f((ushort)(uv.y >> 16))    + v0.w, 0.f);
    float h4 = fmaxf(bf2f((ushort)(uv.z & 0xffff)) + v1.x, 0.f);
    float h5 = fmaxf(bf2f((ushort)(uv.z >> 16))    + v1.y, 0.f);
    float h6 = fmaxf(bf2f((ushort)(uv.w & 0xffff)) + v1.z, 0.f);
    float h7 = fmaxf(bf2f((ushort)(uv.w >> 16))    + v1.w, 0.f);
    uint4 pk;
    pk.x = (uint)f2bf(h0) | ((uint)f2bf(h1) << 16);
    pk.y = (uint)f2bf(h2) | ((uint)f2bf(h3) << 16);
    pk.z = (uint)f2bf(h4) | ((uint)f2bf(h5) << 16);
    pk.w = (uint)f2bf(h6) | ((uint)f2bf(h7) << 16);
    int row = (w << 6) + e_loc;
    int byte = (row * 128 + c0 * 2) ^ ((row & 7) << 4);
    *(uint4*)(h1s + byte) = pk;
  }
  __syncthreads();

  short8 bfr[8][2];
  #pragma unroll
  for (int nt = 0; nt < 8; ++nt) {
    #pragma unroll
    for (int ks = 0; ks < 2; ++ks) {
      int row = nt * 16 + (l & 15);
      int byte = (row * 128 + ks * 64 + (l >> 4) * 16) ^ ((row & 7) << 4);
      bfr[nt][ks] = *(const short8*)(w2s + byte);
    }
  }
  float bias0 = b2[l], bias1 = b2[64 + l];

  #pragma unroll
  for (int pt = 0; pt < 2; ++pt) {
    int rbase = (w << 6) + (pt << 5);
    short8 a[2][2];
    #pragma unroll
    for (int m = 0; m < 2; ++m) {
      #pragma unroll
      for (int ks = 0; ks < 2; ++ks) {
        int row = rbase + m * 16 + (l & 15);
        int byte = (row * 128 + ks * 64 + (l >> 4) * 16) ^ ((row & 7) << 4);
        a[m][ks] = *(const short8*)(h1s + byte);
      }
    }
    float r03 = 0.f, r47 = 0.f;
    #pragma unroll
    for (int nt = 0; nt < 8; ++nt) {
      f32x4 acc0 = {0.f, 0.f, 0.f, 0.f}, acc1 = {0.f, 0.f, 0.f, 0.f};
      acc0 = __builtin_amdgcn_mfma_f32_16x16x32_bf16(a[0][0], bfr[nt][0], acc0, 0, 0, 0);
      acc0 = __builtin_amdgcn_mfma_f32_16x16x32_bf16(a[0][1], bfr[nt][1], acc0, 0, 0, 0);
      acc1 = __builtin_amdgcn_mfma_f32_16x16x32_bf16(a[1][0], bfr[nt][0], acc1, 0, 0, 0);
      acc1 = __builtin_amdgcn_mfma_f32_16x16x32_bf16(a[1][1], bfr[nt][1], acc1, 0, 0, 0);
      float m0 = fmaxf(fmaxf(fmaxf(acc0[0], acc1[0]), fmaxf(acc0[1], acc1[1])),
                       fmaxf(fmaxf(acc0[2], acc1[2]), fmaxf(acc0[3], acc1[3])));
      m0 = fmaxf(m0, __shfl_xor(m0, 16, 64));
      m0 = fmaxf(m0, __shfl_xor(m0, 32, 64));
      if ((l >> 4) == (nt & 3)) { if (nt < 4) r03 = m0; else r47 = m0; }
    }
    int pg = p0 + (w << 1) + pt;
    h128[(size_t)pg * 128 + l]      = fmaxf(r03 + bias0, 0.f);
    h128[(size_t)pg * 128 + 64 + l] = fmaxf(r47 + bias1, 0.f);
  }
}

// ---------- K4: inter via MFMA (unchanged) ----------
__global__ __launch_bounds__(256, 2) void inter_kernel(
    const float* __restrict__ h128, const ushort* __restrict__ W3b,
    float* __restrict__ partial) {
  __shared__ __align__(16) char as_[32 * 256];   // 8 KB
  int tid = threadIdx.x, w = tid >> 6, l = tid & 63;
  int chunk = blockIdx.x;
  const float* hp = h128 + (size_t)chunk * 32 * 128;

  {
    int row = tid >> 3, c0 = (tid & 7) * 16;
    const float4* src = reinterpret_cast<const float4*>(hp + row * 128 + c0);
    float4 f0 = src[0], f1 = src[1], f2 = src[2], f3 = src[3];
    uint4 p0, p1;
    p0.x = (uint)f2bf(f0.x) | ((uint)f2bf(f0.y) << 16);
    p0.y = (uint)f2bf(f0.z) | ((uint)f2bf(f0.w) << 16);
    p0.z = (uint)f2bf(f1.x) | ((uint)f2bf(f1.y) << 16);
    p0.w = (uint)f2bf(f1.z) | ((uint)f2bf(f1.w) << 16);
    p1.x = (uint)f2bf(f2.x) | ((uint)f2bf(f2.y) << 16);
    p1.y = (uint)f2bf(f2.z) | ((uint)f2bf(f2.w) << 16);
    p1.z = (uint)f2bf(f3.x) | ((uint)f2bf(f3.y) << 16);
    p1.w = (uint)f2bf(f3.z) | ((uint)f2bf(f3.w) << 16);
    int sw = (row & 7) << 4;
    *(uint4*)(as_ + ((row * 256 + c0 * 2) ^ sw))      = p0;
    *(uint4*)(as_ + ((row * 256 + c0 * 2 + 16) ^ sw)) = p1;
  }
  __syncthreads();

  short8 a[2][4];
  #pragma unroll
  for (int m = 0; m < 2; ++m) {
    #pragma unroll
    for (int ks = 0; ks < 4; ++ks) {
      int row = m * 16 + (l & 15);
      int byte = (row * 256 + ks * 64 + (l >> 4) * 16) ^ ((row & 7) << 4);
      a[m][ks] = *(const short8*)(as_ + byte);
    }
  }

  const ushort* wb = W3b + (size_t)(w * 256) * 128;
  float res[4];
  #pragma unroll
  for (int nt = 0; nt < 16; ++nt) {
    f32x4 acc0 = {0.f, 0.f, 0.f, 0.f}, acc1 = {0.f, 0.f, 0.f, 0.f};
    #pragma unroll
    for (int ks = 0; ks < 4; ++ks) {
      short8 bf = *(const short8*)(wb + (size_t)(nt * 16 + (l & 15)) * 128
                                      + ks * 32 + (l >> 4) * 8);
      acc0 = __builtin_amdgcn_mfma_f32_16x16x32_bf16(a[0][ks], bf, acc0, 0, 0, 0);
      acc1 = __builtin_amdgcn_mfma_f32_16x16x32_bf16(a[1][ks], bf, acc1, 0, 0, 0);
    }
    float m0 = fmaxf(fmaxf(fmaxf(acc0[0], acc1[0]), fmaxf(acc0[1], acc1[1])),
                     fmaxf(fmaxf(acc0[2], acc1[2]), fmaxf(acc0[3], acc1[3])));
    m0 = fmaxf(m0, __shfl_xor(m0, 16, 64));
    m0 = fmaxf(m0, __shfl_xor(m0, 32, 64));
    if ((l >> 4) == (nt & 3)) res[nt >> 2] = m0;
  }
  float* pp = partial + (size_t)chunk * 1024 + w * 256;
  #pragma unroll
  for (int g = 0; g < 4; ++g) pp[g * 64 + l] = res[g];
}

// ---------- K5: global max over chunks + bias + relu (32 blocks) ----------
__global__ __launch_bounds__(256) void gmax_kernel(const float* __restrict__ partial,
                                                   const float* __restrict__ b3,
                                                   float* __restrict__ g) {
  int t = blockIdx.x * 256 + threadIdx.x;
  if (t >= B_SZ * 1024) return;
  int b = t >> 10, ch = t & 1023;
  const float* p = partial + (size_t)b * 128 * 1024 + ch;
  float m = -3.0e38f;
  for (int i = 0; i < 128; ++i) m = fmaxf(m, p[(size_t)i * 1024]);
  g[t] = fmaxf(m + b3[ch], 0.0f);
}

// ---------- K6/7/8: small FCs, one wave per output (parallel over weight rows) ----------
__global__ __launch_bounds__(64) void fc_kernel(const float* __restrict__ in,
                                                const float* __restrict__ W,
                                                const float* __restrict__ bias,
                                                float* __restrict__ out,
                                                int in_dim, int out_dim, int mode) {
  int blk = blockIdx.x;
  int b = blk / out_dim, o = blk % out_dim;
  int lane = threadIdx.x;
  const float* iv = in + (size_t)b * in_dim;
  const float* w  = W  + (size_t)o * in_dim;
  float s = 0.f;
  for (int c = lane; c < in_dim; c += 64) s += iv[c] * w[c];
  #pragma unroll
  for (int off = 32; off; off >>= 1) s += __shfl_down(s, off);
  if (lane == 0) {
    float r = s + bias[o];
    if (mode == 0) r = fmaxf(r, 0.0f);
    else if (o == 0 || o == 4 || o == 8) r += 1.0f;
    out[blk] = r;
  }
}

extern "C" void kernel_launch(void* const* d_in, const int* in_sizes, int n_in,
                              void* d_out, int out_size, void* d_ws, size_t ws_size,
                              hipStream_t stream) {
  const float* x  = (const float*)d_in[0];
  const float* W1 = (const float*)d_in[1];
  const float* b1 = (const float*)d_in[2];
  const float* W2 = (const float*)d_in[3];
  const float* b2 = (const float*)d_in[4];
  const float* W3 = (const float*)d_in[5];
  const float* b3 = (const float*)d_in[6];
  const float* W4 = (const float*)d_in[7];
  const float* b4 = (const float*)d_in[8];
  const float* W5 = (const float*)d_in[9];
  const float* b5 = (const float*)d_in[10];
  const float* W6 = (const float*)d_in[11];
  const float* b6 = (const float*)d_in[12];
  float* out = (float*)d_out;

  char* ws = (char*)d_ws;
  ushort* u_bf = (ushort*)(ws);                  // [0,4M)   dead after edge_kernel
  int*   idxb  = (int*)  (ws + (8u  << 20));     // [8,10.5M) dead after edge_kernel
  float* h128  = (float*)(ws + (11u << 20));     // [11,27M)
  ushort* W3b  = (ushort*)(ws + (27u << 20));    // [27,27.25M)
  float* part  = (float*)(ws);                   // [0,4M)  over dead u
  float* g     = (float*)(ws + (5u  << 20));
  float* g4    = (float*)(ws + (6u  << 20));
  float* g5    = (float*)(ws + (7u  << 20));

  hipLaunchKernelGGL(prep_kernel, dim3(8256), dim3(256), 0, stream, x, W1, W3, u_bf, W3b);
  hipLaunchKernelGGL(knn_kernel,  dim3(8192), dim3(256), 0, stream, x, idxb);
  hipLaunchKernelGGL(edge_kernel, dim3(NTOT / PPB), dim3(256), 0, stream,
                     x, W1, b1, W2, b2, u_bf, idxb, h128);
  hipLaunchKernelGGL(inter_kernel, dim3(1024), dim3(256), 0, stream, h128, W3b, part);
  hipLaunchKernelGGL(gmax_kernel, dim3(32), dim3(256), 0, stream, part, b3, g);
  hipLaunchKernelGGL(fc_kernel, dim3(B_SZ * 512), dim3(64), 0, stream, g,  W4, b4, g4, 1024, 512, 0);
  hipLaunchKernelGGL(fc_kernel, dim3(B_SZ * 256), dim3(64), 0, stream, g4, W5, b5, g5, 512, 256, 0);
  hipLaunchKernelGGL(fc_kernel, dim3(B_SZ * 9),   dim3(64), 0, stream, g5, W6, b6, out, 256, 9, 1);
}